// Round 1
// baseline (11457.961 us; speedup 1.0000x reference)
//
#include <hip/hip_runtime.h>
#include <math.h>

#define B_ 2
#define L_ 1024
#define D_ 768
#define NL_ 8
#define DI_ 1536
#define NS_ 16
#define DR_ 48
#define KC_ 4
#define EPS_ 1e-5f
#define M_ (B_*L_)   // 2048 rows

// ---------------- block reduction helper (256 threads = 4 waves) ------------
__device__ __forceinline__ float block_sum256(float v) {
    __shared__ float sb[4];
    #pragma unroll
    for (int o = 32; o > 0; o >>= 1) v += __shfl_down(v, o);
    if ((threadIdx.x & 63) == 0) sb[threadIdx.x >> 6] = v;
    __syncthreads();
    float r = sb[0] + sb[1] + sb[2] + sb[3];
    __syncthreads();
    return r;
}

// ---------------- init: xcur = x, res = 0 -----------------------------------
__global__ void init_kernel(const float* __restrict__ x,
                            float* __restrict__ xcur,
                            float* __restrict__ res, int n) {
    int i = blockIdx.x * blockDim.x + threadIdx.x;
    if (i < n) { xcur[i] = x[i]; res[i] = 0.f; }
}

// ---------------- fused residual-accumulate + LayerNorm ---------------------
// res += xcur;  xn = LN(xcur)*w + b     (one block per row, D=768 = 3*256)
__global__ __launch_bounds__(256) void ln_res_kernel(
    const float* __restrict__ xcur, float* __restrict__ res,
    const float* __restrict__ w, const float* __restrict__ b,
    float* __restrict__ xn) {
    int row = blockIdx.x;
    int t = threadIdx.x;
    size_t base = (size_t)row * D_;
    float v0 = xcur[base + t];
    float v1 = xcur[base + t + 256];
    float v2 = xcur[base + t + 512];
    res[base + t]       += v0;
    res[base + t + 256] += v1;
    res[base + t + 512] += v2;
    float mu = block_sum256(v0 + v1 + v2) * (1.0f / D_);
    float d0 = v0 - mu, d1 = v1 - mu, d2 = v2 - mu;
    float var = block_sum256(d0 * d0 + d1 * d1 + d2 * d2) * (1.0f / D_);
    float rs = rsqrtf(var + EPS_);
    xn[base + t]       = d0 * rs * w[t]       + b[t];
    xn[base + t + 256] = d1 * rs * w[t + 256] + b[t + 256];
    xn[base + t + 512] = d2 * rs * w[t + 512] + b[t + 512];
}

// ---------------- final LN: out = LN(xcur + res) ----------------------------
__global__ __launch_bounds__(256) void final_ln_kernel(
    const float* __restrict__ xcur, const float* __restrict__ res,
    const float* __restrict__ w, const float* __restrict__ b,
    float* __restrict__ out) {
    int row = blockIdx.x;
    int t = threadIdx.x;
    size_t base = (size_t)row * D_;
    float v0 = xcur[base + t]       + res[base + t];
    float v1 = xcur[base + t + 256] + res[base + t + 256];
    float v2 = xcur[base + t + 512] + res[base + t + 512];
    float mu = block_sum256(v0 + v1 + v2) * (1.0f / D_);
    float d0 = v0 - mu, d1 = v1 - mu, d2 = v2 - mu;
    float var = block_sum256(d0 * d0 + d1 * d1 + d2 * d2) * (1.0f / D_);
    float rs = rsqrtf(var + EPS_);
    out[base + t]       = d0 * rs * w[t]       + b[t];
    out[base + t + 256] = d1 * rs * w[t + 256] + b[t + 256];
    out[base + t + 512] = d2 * rs * w[t + 512] + b[t + 512];
}

// ---------------- generic fp32 GEMM: C[M,N] = A[M,K] * W[N,K]^T (+bias,+act) -
// ACT: 0 = none, 1 = softplus
template<int ACT>
__global__ __launch_bounds__(256) void gemm_kernel(
    const float* __restrict__ A, int lda,
    const float* __restrict__ W,          // N x K, row-major
    const float* __restrict__ bias,       // may be null
    float* __restrict__ C, int ldc,
    int M, int N, int K) {
    const int BM = 64, BN = 64, BK = 16;
    __shared__ float sA[BK][BM + 1];
    __shared__ float sW[BK][BN + 1];
    int bm = blockIdx.y * BM, bn = blockIdx.x * BN;
    int tid = threadIdx.x;
    int tx = tid & 15, ty = tid >> 4;
    float acc[4][4] = {};
    for (int k0 = 0; k0 < K; k0 += BK) {
        #pragma unroll
        for (int r = 0; r < 4; r++) {
            int j = tid + 256 * r;
            int k = j & 15, m = j >> 4;
            sA[k][m] = A[(size_t)(bm + m) * lda + k0 + k];   // M always %64==0
        }
        #pragma unroll
        for (int r = 0; r < 4; r++) {
            int j = tid + 256 * r;
            int k = j & 15, n = j >> 4;
            int col = bn + n;
            sW[k][n] = (col < N) ? W[(size_t)col * K + k0 + k] : 0.f;
        }
        __syncthreads();
        #pragma unroll
        for (int k = 0; k < BK; k++) {
            float a[4], w[4];
            #pragma unroll
            for (int i = 0; i < 4; i++) a[i] = sA[k][ty * 4 + i];
            #pragma unroll
            for (int j = 0; j < 4; j++) w[j] = sW[k][tx * 4 + j];
            #pragma unroll
            for (int i = 0; i < 4; i++)
                #pragma unroll
                for (int j = 0; j < 4; j++)
                    acc[i][j] += a[i] * w[j];
        }
        __syncthreads();
    }
    #pragma unroll
    for (int i = 0; i < 4; i++) {
        int m = bm + ty * 4 + i;
        #pragma unroll
        for (int j = 0; j < 4; j++) {
            int n = bn + tx * 4 + j;
            if (n < N) {
                float v = acc[i][j];
                if (bias) v += bias[n];
                if (ACT == 1) v = (v > 20.f) ? v : log1pf(__expf(v));
                C[(size_t)m * ldc + n] = v;
            }
        }
    }
}

// ---------------- causal depthwise conv (K=4) + bias + SiLU -----------------
// xi = xz[..., :DI];  xc[b,t,d] = silu( sum_k xi[b,t+k-3,d]*cw[d,k] + cb[d] )
__global__ void conv_silu_kernel(const float* __restrict__ xz,
                                 const float* __restrict__ cw,
                                 const float* __restrict__ cb,
                                 float* __restrict__ xc) {
    int idx = blockIdx.x * blockDim.x + threadIdx.x;   // over B*L*DI
    if (idx >= B_ * L_ * DI_) return;
    int d = idx % DI_;
    int t = (idx / DI_) % L_;
    int b = idx / (DI_ * L_);
    float acc = cb[d];
    #pragma unroll
    for (int k = 0; k < KC_; k++) {
        int tt = t + k - (KC_ - 1);
        if (tt >= 0)
            acc += xz[((size_t)(b * L_ + tt)) * (2 * DI_) + d] * cw[d * KC_ + k];
    }
    xc[idx] = acc / (1.0f + __expf(-acc));
}

// ---------------- selective scan + skip + gate ------------------------------
// 16 lanes per (b,d) channel; lane n holds state n. Sequential over t.
__global__ __launch_bounds__(256) void scan_kernel(
    const float* __restrict__ dt,    // (B,L,DI)
    const float* __restrict__ dbc,   // (B,L,80): [0:48)=dt_raw, [48:64)=B, [64:80)=C
    const float* __restrict__ xc,    // (B,L,DI)
    const float* __restrict__ xz,    // (B,L,2DI) -> z = [...,DI:2DI]
    const float* __restrict__ A_log, // (DI,NS) this layer
    const float* __restrict__ Dp,    // (DI)
    float* __restrict__ yg) {        // (B,L,DI)
    int lane = threadIdx.x & 15;                                   // state n
    int grp = (blockIdx.x * blockDim.x + threadIdx.x) >> 4;        // channel
    int d = grp % DI_;
    int b = grp / DI_;
    float A = -__expf(A_log[d * NS_ + lane]);
    float Dv = Dp[d];
    float h = 0.f;
    for (int t = 0; t < L_; t++) {
        size_t bt = (size_t)(b * L_ + t);
        float dtv = dt[bt * DI_ + d];
        float xv  = xc[bt * DI_ + d];
        float Bt  = dbc[bt * 80 + DR_ + lane];
        float Ct  = dbc[bt * 80 + DR_ + NS_ + lane];
        h = __expf(dtv * A) * h + dtv * xv * Bt;
        float y = h * Ct;
        y += __shfl_xor(y, 1);
        y += __shfl_xor(y, 2);
        y += __shfl_xor(y, 4);
        y += __shfl_xor(y, 8);
        if (lane == 0) {
            float zv = xz[bt * (2 * DI_) + DI_ + d];
            float yy = y + xv * Dv;
            yy *= zv / (1.0f + __expf(-zv));
            yg[bt * DI_ + d] = yy;
        }
    }
}

extern "C" void kernel_launch(void* const* d_in, const int* in_sizes, int n_in,
                              void* d_out, int out_size, void* d_ws, size_t ws_size,
                              hipStream_t stream) {
    const float* x        = (const float*)d_in[0];
    const float* ln_w     = (const float*)d_in[1];
    const float* ln_b     = (const float*)d_in[2];
    const float* in_proj  = (const float*)d_in[3];
    const float* conv_w   = (const float*)d_in[4];
    const float* conv_b   = (const float*)d_in[5];
    const float* x_proj   = (const float*)d_in[6];
    const float* dt_w     = (const float*)d_in[7];
    const float* dt_b     = (const float*)d_in[8];
    const float* A_log    = (const float*)d_in[9];
    const float* D_skip   = (const float*)d_in[10];
    const float* out_proj = (const float*)d_in[11];
    const float* fn_w     = (const float*)d_in[12];
    const float* fn_b     = (const float*)d_in[13];
    float* out = (float*)d_out;

    float* ws = (float*)d_ws;
    float* xcur = ws; ws += (size_t)M_ * D_;
    float* res  = ws; ws += (size_t)M_ * D_;
    float* xn   = ws; ws += (size_t)M_ * D_;
    float* xz   = ws; ws += (size_t)M_ * 2 * DI_;
    float* xc   = ws; ws += (size_t)M_ * DI_;
    float* dbc  = ws; ws += (size_t)M_ * 80;
    float* dtb  = ws; ws += (size_t)M_ * DI_;
    float* yg   = ws; ws += (size_t)M_ * DI_;

    init_kernel<<<(M_ * D_ + 255) / 256, 256, 0, stream>>>(x, xcur, res, M_ * D_);

    for (int l = 0; l < NL_; l++) {
        ln_res_kernel<<<M_, 256, 0, stream>>>(
            xcur, res, ln_w + l * D_, ln_b + l * D_, xn);

        // xz = xn @ Wi^T   (M=2048, K=768, N=3072)
        gemm_kernel<0><<<dim3((2 * DI_) / 64, M_ / 64), 256, 0, stream>>>(
            xn, D_, in_proj + (size_t)l * 2 * DI_ * D_, nullptr,
            xz, 2 * DI_, M_, 2 * DI_, D_);

        conv_silu_kernel<<<(B_ * L_ * DI_ + 255) / 256, 256, 0, stream>>>(
            xz, conv_w + l * DI_ * KC_, conv_b + l * DI_, xc);

        // dbc = xc @ Wx^T  (M=2048, K=1536, N=80)
        gemm_kernel<0><<<dim3((80 + 63) / 64, M_ / 64), 256, 0, stream>>>(
            xc, DI_, x_proj + (size_t)l * 80 * DI_, nullptr,
            dbc, 80, M_, 80, DI_);

        // dt = softplus(dbc[:, :48] @ Wdt^T + bdt)  (M=2048, K=48, N=1536)
        gemm_kernel<1><<<dim3(DI_ / 64, M_ / 64), 256, 0, stream>>>(
            dbc, 80, dt_w + (size_t)l * DI_ * DR_, dt_b + l * DI_,
            dtb, DI_, M_, DI_, DR_);

        scan_kernel<<<(B_ * DI_ * 16) / 256, 256, 0, stream>>>(
            dtb, dbc, xc, xz, A_log + (size_t)l * DI_ * NS_, D_skip + l * DI_, yg);

        // xcur = yg @ Wo^T  (M=2048, K=1536, N=768)
        gemm_kernel<0><<<dim3(D_ / 64, M_ / 64), 256, 0, stream>>>(
            yg, DI_, out_proj + (size_t)l * D_ * DI_, nullptr,
            xcur, D_, M_, D_, DI_);
    }

    final_ln_kernel<<<M_, 256, 0, stream>>>(xcur, res, fn_w, fn_b, out);
}

// Round 2
// 3735.325 us; speedup vs baseline: 3.0675x; 3.0675x over previous
//
#include <hip/hip_runtime.h>
#include <math.h>

#define B_ 2
#define L_ 1024
#define D_ 768
#define NL_ 8
#define DI_ 1536
#define NS_ 16
#define DR_ 48
#define KC_ 4
#define EPS_ 1e-5f
#define M_ (B_*L_)   // 2048 rows
#define NC_ 8        // scan chunks
#define T_ 128       // chunk length (NC_*T_ == L_)

typedef short bf16x8 __attribute__((ext_vector_type(8)));
typedef float f32x4  __attribute__((ext_vector_type(4)));

// ---------------- fp32 -> bf16 (RNE) ---------------------------------------
__device__ __forceinline__ unsigned short f2bf(float f) {
    union { float f; unsigned int u; } v; v.f = f;
    unsigned int u = v.u;
    u += 0x7fffu + ((u >> 16) & 1u);
    return (unsigned short)(u >> 16);
}

__global__ void convert_bf16_kernel(const float* __restrict__ src,
                                    unsigned short* __restrict__ dst, int n) {
    int i = blockIdx.x * blockDim.x + threadIdx.x;
    if (i < n) dst[i] = f2bf(src[i]);
}

// ---------------- block reduction helper (256 threads = 4 waves) ------------
__device__ __forceinline__ float block_sum256(float v) {
    __shared__ float sb[4];
    #pragma unroll
    for (int o = 32; o > 0; o >>= 1) v += __shfl_down(v, o);
    if ((threadIdx.x & 63) == 0) sb[threadIdx.x >> 6] = v;
    __syncthreads();
    float r = sb[0] + sb[1] + sb[2] + sb[3];
    __syncthreads();
    return r;
}

// ---------------- init: xcur = x, res = 0 -----------------------------------
__global__ void init_kernel(const float* __restrict__ x,
                            float* __restrict__ xcur,
                            float* __restrict__ res, int n) {
    int i = blockIdx.x * blockDim.x + threadIdx.x;
    if (i < n) { xcur[i] = x[i]; res[i] = 0.f; }
}

// ---------------- fused residual-accumulate + LayerNorm (bf16 out) ----------
__global__ __launch_bounds__(256) void ln_res_kernel(
    const float* __restrict__ xcur, float* __restrict__ res,
    const float* __restrict__ w, const float* __restrict__ b,
    unsigned short* __restrict__ xn) {
    int row = blockIdx.x;
    int t = threadIdx.x;
    size_t base = (size_t)row * D_;
    float v0 = xcur[base + t];
    float v1 = xcur[base + t + 256];
    float v2 = xcur[base + t + 512];
    res[base + t]       += v0;
    res[base + t + 256] += v1;
    res[base + t + 512] += v2;
    float mu = block_sum256(v0 + v1 + v2) * (1.0f / D_);
    float d0 = v0 - mu, d1 = v1 - mu, d2 = v2 - mu;
    float var = block_sum256(d0 * d0 + d1 * d1 + d2 * d2) * (1.0f / D_);
    float rs = rsqrtf(var + EPS_);
    xn[base + t]       = f2bf(d0 * rs * w[t]       + b[t]);
    xn[base + t + 256] = f2bf(d1 * rs * w[t + 256] + b[t + 256]);
    xn[base + t + 512] = f2bf(d2 * rs * w[t + 512] + b[t + 512]);
}

// ---------------- final LN: out = LN(xcur + res) ----------------------------
__global__ __launch_bounds__(256) void final_ln_kernel(
    const float* __restrict__ xcur, const float* __restrict__ res,
    const float* __restrict__ w, const float* __restrict__ b,
    float* __restrict__ out) {
    int row = blockIdx.x;
    int t = threadIdx.x;
    size_t base = (size_t)row * D_;
    float v0 = xcur[base + t]       + res[base + t];
    float v1 = xcur[base + t + 256] + res[base + t + 256];
    float v2 = xcur[base + t + 512] + res[base + t + 512];
    float mu = block_sum256(v0 + v1 + v2) * (1.0f / D_);
    float d0 = v0 - mu, d1 = v1 - mu, d2 = v2 - mu;
    float var = block_sum256(d0 * d0 + d1 * d1 + d2 * d2) * (1.0f / D_);
    float rs = rsqrtf(var + EPS_);
    out[base + t]       = d0 * rs * w[t]       + b[t];
    out[base + t + 256] = d1 * rs * w[t + 256] + b[t + 256];
    out[base + t + 512] = d2 * rs * w[t + 512] + b[t + 512];
}

// ---------------- bf16 MFMA GEMM: C[M,N] = A[M,K] * W[N,K]^T ---------------
// 128x128 tile, BK=32, 256 thr = 4 waves, each wave 64x64 (4x4 of 16x16x32).
__global__ __launch_bounds__(256) void gemm_bf16_kernel(
    const unsigned short* __restrict__ A,   // M x K bf16 row-major
    const unsigned short* __restrict__ W,   // N x K bf16 row-major
    float* __restrict__ C, int M, int N, int K) {
    __shared__ unsigned short sA[128 * 32];
    __shared__ unsigned short sW[128 * 32];
    int bm = blockIdx.y * 128, bn = blockIdx.x * 128;
    int tid = threadIdx.x;
    int wave = tid >> 6, lane = tid & 63;
    int wrow = (wave & 1) * 64, wcol = (wave >> 1) * 64;
    int quad = lane >> 4, r16 = lane & 15;
    f32x4 acc[4][4];
    #pragma unroll
    for (int i = 0; i < 4; i++)
        #pragma unroll
        for (int j = 0; j < 4; j++)
            acc[i][j] = (f32x4){0.f, 0.f, 0.f, 0.f};

    int srow = tid >> 2;              // 0..63
    int scol = (tid & 3) * 8;         // 0,8,16,24
    for (int k0 = 0; k0 < K; k0 += 32) {
        // stage A: 128x32 = 4096 ushorts; each thread two 16B chunks
        *(uint4*)&sA[tid * 8] =
            *(const uint4*)&A[(size_t)(bm + srow) * K + k0 + scol];
        *(uint4*)&sA[2048 + tid * 8] =
            *(const uint4*)&A[(size_t)(bm + 64 + srow) * K + k0 + scol];
        *(uint4*)&sW[tid * 8] =
            *(const uint4*)&W[(size_t)(bn + srow) * K + k0 + scol];
        *(uint4*)&sW[2048 + tid * 8] =
            *(const uint4*)&W[(size_t)(bn + 64 + srow) * K + k0 + scol];
        __syncthreads();
        bf16x8 af[4], wf[4];
        #pragma unroll
        for (int i = 0; i < 4; i++)
            af[i] = *(const bf16x8*)&sA[(wrow + i * 16 + r16) * 32 + quad * 8];
        #pragma unroll
        for (int j = 0; j < 4; j++)
            wf[j] = *(const bf16x8*)&sW[(wcol + j * 16 + r16) * 32 + quad * 8];
        #pragma unroll
        for (int i = 0; i < 4; i++)
            #pragma unroll
            for (int j = 0; j < 4; j++)
                acc[i][j] = __builtin_amdgcn_mfma_f32_16x16x32_bf16(
                    af[i], wf[j], acc[i][j], 0, 0, 0);
        __syncthreads();
    }
    // epilogue: D row = quad*4+reg, col = r16 within each 16x16 tile
    #pragma unroll
    for (int i = 0; i < 4; i++) {
        #pragma unroll
        for (int j = 0; j < 4; j++) {
            int col = bn + wcol + j * 16 + r16;
            #pragma unroll
            for (int reg = 0; reg < 4; reg++) {
                int row = bm + wrow + i * 16 + quad * 4 + reg;
                C[(size_t)row * N + col] = acc[i][j][reg];
            }
        }
    }
}

// ---------------- generic fp32 GEMM (small shapes): C = A*W^T (+bias,+act) --
template<int ACT>
__global__ __launch_bounds__(256) void gemm_kernel(
    const float* __restrict__ A, int lda,
    const float* __restrict__ W,
    const float* __restrict__ bias,
    float* __restrict__ C, int ldc,
    int M, int N, int K) {
    const int BM = 64, BN = 64, BK = 16;
    __shared__ float sA[BK][BM + 1];
    __shared__ float sW[BK][BN + 1];
    int bm = blockIdx.y * BM, bn = blockIdx.x * BN;
    int tid = threadIdx.x;
    int tx = tid & 15, ty = tid >> 4;
    float acc[4][4] = {};
    for (int k0 = 0; k0 < K; k0 += BK) {
        #pragma unroll
        for (int r = 0; r < 4; r++) {
            int j = tid + 256 * r;
            int k = j & 15, m = j >> 4;
            sA[k][m] = A[(size_t)(bm + m) * lda + k0 + k];
        }
        #pragma unroll
        for (int r = 0; r < 4; r++) {
            int j = tid + 256 * r;
            int k = j & 15, n = j >> 4;
            int col = bn + n;
            sW[k][n] = (col < N) ? W[(size_t)col * K + k0 + k] : 0.f;
        }
        __syncthreads();
        #pragma unroll
        for (int k = 0; k < BK; k++) {
            float a[4], w[4];
            #pragma unroll
            for (int i = 0; i < 4; i++) a[i] = sA[k][ty * 4 + i];
            #pragma unroll
            for (int j = 0; j < 4; j++) w[j] = sW[k][tx * 4 + j];
            #pragma unroll
            for (int i = 0; i < 4; i++)
                #pragma unroll
                for (int j = 0; j < 4; j++)
                    acc[i][j] += a[i] * w[j];
        }
        __syncthreads();
    }
    #pragma unroll
    for (int i = 0; i < 4; i++) {
        int m = bm + ty * 4 + i;
        #pragma unroll
        for (int j = 0; j < 4; j++) {
            int n = bn + tx * 4 + j;
            if (n < N) {
                float v = acc[i][j];
                if (bias) v += bias[n];
                if (ACT == 1) v = (v > 20.f) ? v : log1pf(__expf(v));
                C[(size_t)m * ldc + n] = v;
            }
        }
    }
}

// ---------------- causal depthwise conv (K=4) + bias + SiLU -----------------
__global__ void conv_silu_kernel(const float* __restrict__ xz,
                                 const float* __restrict__ cw,
                                 const float* __restrict__ cb,
                                 float* __restrict__ xc) {
    int idx = blockIdx.x * blockDim.x + threadIdx.x;   // over B*L*DI
    if (idx >= B_ * L_ * DI_) return;
    int d = idx % DI_;
    int t = (idx / DI_) % L_;
    int b = idx / (DI_ * L_);
    float acc = cb[d];
    #pragma unroll
    for (int k = 0; k < KC_; k++) {
        int tt = t + k - (KC_ - 1);
        if (tt >= 0)
            acc += xz[((size_t)(b * L_ + tt)) * (2 * DI_) + d] * cw[d * KC_ + k];
    }
    xc[idx] = acc / (1.0f + __expf(-acc));
}

// ---------------- scan pass 1: per-chunk decay product + local endpoint -----
// group = 16 lanes per (b,chunk,d); lane n = state index
__global__ __launch_bounds__(256) void scan_part1(
    const float* __restrict__ dt, const float* __restrict__ dbc,
    const float* __restrict__ xc, const float* __restrict__ A_log,
    float* __restrict__ Pbuf, float* __restrict__ Sbuf) {
    int lane = threadIdx.x & 15;
    int grp = (blockIdx.x * 256 + threadIdx.x) >> 4;   // b*NC*DI + c*DI + d
    int d = grp % DI_;
    int c = (grp / DI_) % NC_;
    int b = grp / (DI_ * NC_);
    float A = -__expf(A_log[d * NS_ + lane]);
    float h = 0.f, sd = 0.f;
    int t0 = c * T_;
    for (int t = t0; t < t0 + T_; t++) {
        size_t bt = (size_t)(b * L_ + t);
        float dtv = dt[bt * DI_ + d];
        float xv  = xc[bt * DI_ + d];
        float Bt  = dbc[bt * 80 + DR_ + lane];
        h = __expf(dtv * A) * h + dtv * xv * Bt;
        sd += dtv;
    }
    size_t o = (((size_t)b * NC_ + c) * DI_ + d) * NS_ + lane;
    Pbuf[o] = __expf(A * sd);
    Sbuf[o] = h;
}

// ---------------- scan pass 2: sequential combine over chunks ---------------
__global__ __launch_bounds__(256) void scan_part2(
    const float* __restrict__ P, const float* __restrict__ S,
    float* __restrict__ hin) {
    int i = blockIdx.x * 256 + threadIdx.x;   // over B*DI*NS
    int b = i / (DI_ * NS_);
    int rem = i % (DI_ * NS_);
    float h = 0.f;
    #pragma unroll
    for (int c = 0; c < NC_; c++) {
        size_t o = ((size_t)b * NC_ + c) * (DI_ * NS_) + rem;
        hin[o] = h;
        h = P[o] * h + S[o];
    }
}

// ---------------- scan pass 3: rescan chunk with init state, gate, bf16 out -
__global__ __launch_bounds__(256) void scan_part3(
    const float* __restrict__ dt, const float* __restrict__ dbc,
    const float* __restrict__ xc, const float* __restrict__ xz,
    const float* __restrict__ A_log, const float* __restrict__ Dp,
    const float* __restrict__ hin, unsigned short* __restrict__ yg) {
    int lane = threadIdx.x & 15;
    int grp = (blockIdx.x * 256 + threadIdx.x) >> 4;
    int d = grp % DI_;
    int c = (grp / DI_) % NC_;
    int b = grp / (DI_ * NC_);
    float A = -__expf(A_log[d * NS_ + lane]);
    float Dv = Dp[d];
    float h = hin[(((size_t)b * NC_ + c) * DI_ + d) * NS_ + lane];
    int t0 = c * T_;
    for (int t = t0; t < t0 + T_; t++) {
        size_t bt = (size_t)(b * L_ + t);
        float dtv = dt[bt * DI_ + d];
        float xv  = xc[bt * DI_ + d];
        float Bt  = dbc[bt * 80 + DR_ + lane];
        float Ct  = dbc[bt * 80 + DR_ + NS_ + lane];
        h = __expf(dtv * A) * h + dtv * xv * Bt;
        float y = h * Ct;
        y += __shfl_xor(y, 1);
        y += __shfl_xor(y, 2);
        y += __shfl_xor(y, 4);
        y += __shfl_xor(y, 8);
        if (lane == 0) {
            float zv = xz[bt * (2 * DI_) + DI_ + d];
            float yy = y + xv * Dv;
            yy *= zv / (1.0f + __expf(-zv));
            yg[bt * DI_ + d] = f2bf(yy);
        }
    }
}

extern "C" void kernel_launch(void* const* d_in, const int* in_sizes, int n_in,
                              void* d_out, int out_size, void* d_ws, size_t ws_size,
                              hipStream_t stream) {
    const float* x        = (const float*)d_in[0];
    const float* ln_w     = (const float*)d_in[1];
    const float* ln_b     = (const float*)d_in[2];
    const float* in_proj  = (const float*)d_in[3];
    const float* conv_w   = (const float*)d_in[4];
    const float* conv_b   = (const float*)d_in[5];
    const float* x_proj   = (const float*)d_in[6];
    const float* dt_w     = (const float*)d_in[7];
    const float* dt_b     = (const float*)d_in[8];
    const float* A_log    = (const float*)d_in[9];
    const float* D_skip   = (const float*)d_in[10];
    const float* out_proj = (const float*)d_in[11];
    const float* fn_w     = (const float*)d_in[12];
    const float* fn_b     = (const float*)d_in[13];
    float* out = (float*)d_out;

    char* p = (char*)d_ws;
    auto alloc = [&](size_t bytes) {
        char* r = p;
        p += (bytes + 255) & ~(size_t)255;
        return (void*)r;
    };
    float* xcur = (float*)alloc((size_t)M_ * D_ * 4);
    float* res  = (float*)alloc((size_t)M_ * D_ * 4);
    unsigned short* xn = (unsigned short*)alloc((size_t)M_ * D_ * 2);
    float* xz   = (float*)alloc((size_t)M_ * 2 * DI_ * 4);
    float* xc   = (float*)alloc((size_t)M_ * DI_ * 4);
    float* dbc  = (float*)alloc((size_t)M_ * 80 * 4);
    float* dtb  = (float*)alloc((size_t)M_ * DI_ * 4);
    unsigned short* yg = (unsigned short*)alloc((size_t)M_ * DI_ * 2);
    float* Pbuf = (float*)alloc((size_t)B_ * NC_ * DI_ * NS_ * 4);
    float* Sbuf = (float*)alloc((size_t)B_ * NC_ * DI_ * NS_ * 4);
    float* hin  = (float*)alloc((size_t)B_ * NC_ * DI_ * NS_ * 4);
    const size_t n_wi = (size_t)NL_ * 2 * DI_ * D_;   // 18.87M
    const size_t n_wo = (size_t)NL_ * D_ * DI_;       // 9.44M
    unsigned short* wi_bf = (unsigned short*)alloc(n_wi * 2);
    unsigned short* wo_bf = (unsigned short*)alloc(n_wo * 2);

    // one-time-per-call weight conversion
    convert_bf16_kernel<<<(n_wi + 255) / 256, 256, 0, stream>>>(in_proj, wi_bf, (int)n_wi);
    convert_bf16_kernel<<<(n_wo + 255) / 256, 256, 0, stream>>>(out_proj, wo_bf, (int)n_wo);

    init_kernel<<<(M_ * D_ + 255) / 256, 256, 0, stream>>>(x, xcur, res, M_ * D_);

    for (int l = 0; l < NL_; l++) {
        ln_res_kernel<<<M_, 256, 0, stream>>>(
            xcur, res, ln_w + l * D_, ln_b + l * D_, xn);

        // xz = xn @ Wi^T   (M=2048, N=3072, K=768)  bf16 MFMA
        gemm_bf16_kernel<<<dim3((2 * DI_) / 128, M_ / 128), 256, 0, stream>>>(
            xn, wi_bf + (size_t)l * 2 * DI_ * D_, xz, M_, 2 * DI_, D_);

        conv_silu_kernel<<<(B_ * L_ * DI_ + 255) / 256, 256, 0, stream>>>(
            xz, conv_w + l * DI_ * KC_, conv_b + l * DI_, xc);

        // dbc = xc @ Wx^T  (M=2048, N=80, K=1536)  fp32
        gemm_kernel<0><<<dim3((80 + 63) / 64, M_ / 64), 256, 0, stream>>>(
            xc, DI_, x_proj + (size_t)l * 80 * DI_, nullptr,
            dbc, 80, M_, 80, DI_);

        // dt = softplus(dbc[:, :48] @ Wdt^T + bdt)  (M=2048, N=1536, K=48) fp32
        gemm_kernel<1><<<dim3(DI_ / 64, M_ / 64), 256, 0, stream>>>(
            dbc, 80, dt_w + (size_t)l * DI_ * DR_, dt_b + l * DI_,
            dtb, DI_, M_, DI_, DR_);

        // chunked selective scan
        scan_part1<<<(B_ * NC_ * DI_ * 16) / 256, 256, 0, stream>>>(
            dtb, dbc, xc, A_log + (size_t)l * DI_ * NS_, Pbuf, Sbuf);
        scan_part2<<<(B_ * DI_ * NS_) / 256, 256, 0, stream>>>(Pbuf, Sbuf, hin);
        scan_part3<<<(B_ * NC_ * DI_ * 16) / 256, 256, 0, stream>>>(
            dtb, dbc, xc, xz, A_log + (size_t)l * DI_ * NS_, D_skip + l * DI_,
            hin, yg);

        // xcur = yg @ Wo^T  (M=2048, N=768, K=1536)  bf16 MFMA
        gemm_bf16_kernel<<<dim3(D_ / 128, M_ / 128), 256, 0, stream>>>(
            yg, wo_bf + (size_t)l * D_ * DI_, xcur, M_, D_, DI_);
    }

    final_ln_kernel<<<M_, 256, 0, stream>>>(xcur, res, fn_w, fn_b, out);
}

// Round 3
// 2233.644 us; speedup vs baseline: 5.1297x; 1.6723x over previous
//
#include <hip/hip_runtime.h>
#include <math.h>

#define B_ 2
#define L_ 1024
#define D_ 768
#define NL_ 8
#define DI_ 1536
#define NS_ 16
#define DR_ 48
#define KC_ 4
#define EPS_ 1e-5f
#define M_ (B_*L_)   // 2048 rows
#define NC_ 8        // scan chunks
#define T_ 128       // chunk length (NC_*T_ == L_)
#define KS_ 16       // x_proj split-K factor
#define KCH_ (DI_/KS_)   // 96 per split

typedef short bf16x8 __attribute__((ext_vector_type(8)));
typedef float f32x4  __attribute__((ext_vector_type(4)));

// ---------------- fp32 -> bf16 (RNE) ---------------------------------------
__device__ __forceinline__ unsigned short f2bf(float f) {
    union { float f; unsigned int u; } v; v.f = f;
    unsigned int u = v.u;
    u += 0x7fffu + ((u >> 16) & 1u);
    return (unsigned short)(u >> 16);
}

__global__ void convert_bf16_kernel(const float* __restrict__ src,
                                    unsigned short* __restrict__ dst, int n) {
    int i = blockIdx.x * blockDim.x + threadIdx.x;
    if (i < n) dst[i] = f2bf(src[i]);
}

// ---------------- block reduction helper (256 threads = 4 waves) ------------
__device__ __forceinline__ float block_sum256(float v) {
    __shared__ float sb[4];
    #pragma unroll
    for (int o = 32; o > 0; o >>= 1) v += __shfl_down(v, o);
    if ((threadIdx.x & 63) == 0) sb[threadIdx.x >> 6] = v;
    __syncthreads();
    float r = sb[0] + sb[1] + sb[2] + sb[3];
    __syncthreads();
    return r;
}

// ---------------- init: xcur = x, res = 0 -----------------------------------
__global__ void init_kernel(const float* __restrict__ x,
                            float* __restrict__ xcur,
                            float* __restrict__ res, int n) {
    int i = blockIdx.x * blockDim.x + threadIdx.x;
    if (i < n) { xcur[i] = x[i]; res[i] = 0.f; }
}

// ---------------- fused residual-accumulate + LayerNorm (bf16 out) ----------
__global__ __launch_bounds__(256) void ln_res_kernel(
    const float* __restrict__ xcur, float* __restrict__ res,
    const float* __restrict__ w, const float* __restrict__ b,
    unsigned short* __restrict__ xn) {
    int row = blockIdx.x;
    int t = threadIdx.x;
    size_t base = (size_t)row * D_;
    float v0 = xcur[base + t];
    float v1 = xcur[base + t + 256];
    float v2 = xcur[base + t + 512];
    res[base + t]       += v0;
    res[base + t + 256] += v1;
    res[base + t + 512] += v2;
    float mu = block_sum256(v0 + v1 + v2) * (1.0f / D_);
    float d0 = v0 - mu, d1 = v1 - mu, d2 = v2 - mu;
    float var = block_sum256(d0 * d0 + d1 * d1 + d2 * d2) * (1.0f / D_);
    float rs = rsqrtf(var + EPS_);
    xn[base + t]       = f2bf(d0 * rs * w[t]       + b[t]);
    xn[base + t + 256] = f2bf(d1 * rs * w[t + 256] + b[t + 256]);
    xn[base + t + 512] = f2bf(d2 * rs * w[t + 512] + b[t + 512]);
}

// ---------------- final LN: out = LN(xcur + res) ----------------------------
__global__ __launch_bounds__(256) void final_ln_kernel(
    const float* __restrict__ xcur, const float* __restrict__ res,
    const float* __restrict__ w, const float* __restrict__ b,
    float* __restrict__ out) {
    int row = blockIdx.x;
    int t = threadIdx.x;
    size_t base = (size_t)row * D_;
    float v0 = xcur[base + t]       + res[base + t];
    float v1 = xcur[base + t + 256] + res[base + t + 256];
    float v2 = xcur[base + t + 512] + res[base + t + 512];
    float mu = block_sum256(v0 + v1 + v2) * (1.0f / D_);
    float d0 = v0 - mu, d1 = v1 - mu, d2 = v2 - mu;
    float var = block_sum256(d0 * d0 + d1 * d1 + d2 * d2) * (1.0f / D_);
    float rs = rsqrtf(var + EPS_);
    out[base + t]       = d0 * rs * w[t]       + b[t];
    out[base + t + 256] = d1 * rs * w[t + 256] + b[t + 256];
    out[base + t + 512] = d2 * rs * w[t + 512] + b[t + 512];
}

// ---------------- bf16 MFMA GEMM: C[M,N] = A[M,K] * W[N,K]^T ---------------
// 128x128 tile, BK=32, 256 thr = 4 waves, each wave 64x64 (4x4 of 16x16x32).
__global__ __launch_bounds__(256) void gemm_bf16_kernel(
    const unsigned short* __restrict__ A,   // M x K bf16 row-major
    const unsigned short* __restrict__ W,   // N x K bf16 row-major
    float* __restrict__ C, int M, int N, int K) {
    __shared__ unsigned short sA[128 * 32];
    __shared__ unsigned short sW[128 * 32];
    int bm = blockIdx.y * 128, bn = blockIdx.x * 128;
    int tid = threadIdx.x;
    int wave = tid >> 6, lane = tid & 63;
    int wrow = (wave & 1) * 64, wcol = (wave >> 1) * 64;
    int quad = lane >> 4, r16 = lane & 15;
    f32x4 acc[4][4];
    #pragma unroll
    for (int i = 0; i < 4; i++)
        #pragma unroll
        for (int j = 0; j < 4; j++)
            acc[i][j] = (f32x4){0.f, 0.f, 0.f, 0.f};

    int srow = tid >> 2;              // 0..63
    int scol = (tid & 3) * 8;         // 0,8,16,24
    for (int k0 = 0; k0 < K; k0 += 32) {
        *(uint4*)&sA[tid * 8] =
            *(const uint4*)&A[(size_t)(bm + srow) * K + k0 + scol];
        *(uint4*)&sA[2048 + tid * 8] =
            *(const uint4*)&A[(size_t)(bm + 64 + srow) * K + k0 + scol];
        *(uint4*)&sW[tid * 8] =
            *(const uint4*)&W[(size_t)(bn + srow) * K + k0 + scol];
        *(uint4*)&sW[2048 + tid * 8] =
            *(const uint4*)&W[(size_t)(bn + 64 + srow) * K + k0 + scol];
        __syncthreads();
        bf16x8 af[4], wf[4];
        #pragma unroll
        for (int i = 0; i < 4; i++)
            af[i] = *(const bf16x8*)&sA[(wrow + i * 16 + r16) * 32 + quad * 8];
        #pragma unroll
        for (int j = 0; j < 4; j++)
            wf[j] = *(const bf16x8*)&sW[(wcol + j * 16 + r16) * 32 + quad * 8];
        #pragma unroll
        for (int i = 0; i < 4; i++)
            #pragma unroll
            for (int j = 0; j < 4; j++)
                acc[i][j] = __builtin_amdgcn_mfma_f32_16x16x32_bf16(
                    af[i], wf[j], acc[i][j], 0, 0, 0);
        __syncthreads();
    }
    #pragma unroll
    for (int i = 0; i < 4; i++) {
        #pragma unroll
        for (int j = 0; j < 4; j++) {
            int col = bn + wcol + j * 16 + r16;
            #pragma unroll
            for (int reg = 0; reg < 4; reg++) {
                int row = bm + wrow + i * 16 + quad * 4 + reg;
                C[(size_t)row * N + col] = acc[i][j][reg];
            }
        }
    }
}

// ---------------- x_proj GEMM: Pb[ks][M][80] partials, bf16 MFMA, split-K ---
// Block: 256 thr = 4 waves; wave w computes rows [bm+w*16, +16) x all 80 cols.
__global__ __launch_bounds__(256) void xproj_gemm_kernel(
    const unsigned short* __restrict__ A,   // M x DI bf16 (xcb)
    const unsigned short* __restrict__ W,   // 80 x DI bf16
    float* __restrict__ Pb) {               // KS x M x 80 partials
    __shared__ unsigned short sA[64 * 32];
    __shared__ unsigned short sW[80 * 32];
    int ks = blockIdx.x;
    int bm = blockIdx.y * 64;
    int tid = threadIdx.x;
    int wave = tid >> 6, lane = tid & 63;
    int quad = lane >> 4, r16 = lane & 15;
    f32x4 acc[5];
    #pragma unroll
    for (int j = 0; j < 5; j++) acc[j] = (f32x4){0.f, 0.f, 0.f, 0.f};
    int k0base = ks * KCH_;
    for (int kc = 0; kc < KCH_; kc += 32) {
        int k0 = k0base + kc;
        {   // stage A: 64x32 = 2048 bf16, one uint4/thread
            int row = tid >> 2, off = (tid & 3) * 8;
            *(uint4*)&sA[row * 32 + off] =
                *(const uint4*)&A[(size_t)(bm + row) * DI_ + k0 + off];
        }
        {   // stage W: 80x32 = 2560 bf16 = 320 chunks of 8
            int row = tid >> 2, off = (tid & 3) * 8;
            *(uint4*)&sW[row * 32 + off] =
                *(const uint4*)&W[(size_t)row * DI_ + k0 + off];
            if (tid < 64) {
                int c = 256 + tid;
                int row2 = c >> 2, off2 = (c & 3) * 8;
                *(uint4*)&sW[row2 * 32 + off2] =
                    *(const uint4*)&W[(size_t)row2 * DI_ + k0 + off2];
            }
        }
        __syncthreads();
        bf16x8 af = *(const bf16x8*)&sA[(wave * 16 + r16) * 32 + quad * 8];
        #pragma unroll
        for (int j = 0; j < 5; j++) {
            bf16x8 wf = *(const bf16x8*)&sW[(j * 16 + r16) * 32 + quad * 8];
            acc[j] = __builtin_amdgcn_mfma_f32_16x16x32_bf16(af, wf, acc[j], 0, 0, 0);
        }
        __syncthreads();
    }
    #pragma unroll
    for (int j = 0; j < 5; j++) {
        int col = j * 16 + r16;
        #pragma unroll
        for (int reg = 0; reg < 4; reg++) {
            int row = bm + wave * 16 + quad * 4 + reg;
            Pb[((size_t)ks * M_ + row) * 80 + col] = acc[j][reg];
        }
    }
}

__global__ void xproj_reduce_kernel(const float* __restrict__ Pb,
                                    float* __restrict__ dbc) {
    int i = blockIdx.x * 256 + threadIdx.x;   // over M_*80
    float s = 0.f;
    #pragma unroll
    for (int ks = 0; ks < KS_; ks++) s += Pb[(size_t)ks * (M_ * 80) + i];
    dbc[i] = s;
}

// ---------------- generic fp32 GEMM (dt: K=48): C = A*W^T (+bias,+softplus) -
template<int ACT>
__global__ __launch_bounds__(256) void gemm_kernel(
    const float* __restrict__ A, int lda,
    const float* __restrict__ W,
    const float* __restrict__ bias,
    float* __restrict__ C, int ldc,
    int M, int N, int K) {
    const int BM = 64, BN = 64, BK = 16;
    __shared__ float sA[BK][BM + 1];
    __shared__ float sW[BK][BN + 1];
    int bm = blockIdx.y * BM, bn = blockIdx.x * BN;
    int tid = threadIdx.x;
    int tx = tid & 15, ty = tid >> 4;
    float acc[4][4] = {};
    for (int k0 = 0; k0 < K; k0 += BK) {
        #pragma unroll
        for (int r = 0; r < 4; r++) {
            int j = tid + 256 * r;
            int k = j & 15, m = j >> 4;
            sA[k][m] = A[(size_t)(bm + m) * lda + k0 + k];
        }
        #pragma unroll
        for (int r = 0; r < 4; r++) {
            int j = tid + 256 * r;
            int k = j & 15, n = j >> 4;
            int col = bn + n;
            sW[k][n] = (col < N) ? W[(size_t)col * K + k0 + k] : 0.f;
        }
        __syncthreads();
        #pragma unroll
        for (int k = 0; k < BK; k++) {
            float a[4], w[4];
            #pragma unroll
            for (int i = 0; i < 4; i++) a[i] = sA[k][ty * 4 + i];
            #pragma unroll
            for (int j = 0; j < 4; j++) w[j] = sW[k][tx * 4 + j];
            #pragma unroll
            for (int i = 0; i < 4; i++)
                #pragma unroll
                for (int j = 0; j < 4; j++)
                    acc[i][j] += a[i] * w[j];
        }
        __syncthreads();
    }
    #pragma unroll
    for (int i = 0; i < 4; i++) {
        int m = bm + ty * 4 + i;
        #pragma unroll
        for (int j = 0; j < 4; j++) {
            int n = bn + tx * 4 + j;
            if (n < N) {
                float v = acc[i][j];
                if (bias) v += bias[n];
                if (ACT == 1) v = (v > 20.f) ? v : log1pf(__expf(v));
                C[(size_t)m * ldc + n] = v;
            }
        }
    }
}

// ---------------- causal depthwise conv (K=4) + bias + SiLU -----------------
// writes fp32 xc (scan) and bf16 xcb (x_proj GEMM operand)
__global__ void conv_silu_kernel(const float* __restrict__ xz,
                                 const float* __restrict__ cw,
                                 const float* __restrict__ cb,
                                 float* __restrict__ xc,
                                 unsigned short* __restrict__ xcb) {
    int idx = blockIdx.x * blockDim.x + threadIdx.x;   // over B*L*DI
    if (idx >= B_ * L_ * DI_) return;
    int d = idx % DI_;
    int t = (idx / DI_) % L_;
    int b = idx / (DI_ * L_);
    float acc = cb[d];
    #pragma unroll
    for (int k = 0; k < KC_; k++) {
        int tt = t + k - (KC_ - 1);
        if (tt >= 0)
            acc += xz[((size_t)(b * L_ + tt)) * (2 * DI_) + d] * cw[d * KC_ + k];
    }
    float v = acc / (1.0f + __expf(-acc));
    xc[idx] = v;
    xcb[idx] = f2bf(v);
}

// ---------------- scan pass 1: per-chunk decay product + local endpoint -----
__global__ __launch_bounds__(256) void scan_part1(
    const float* __restrict__ dt, const float* __restrict__ dbc,
    const float* __restrict__ xc, const float* __restrict__ A_log,
    float* __restrict__ Pbuf, float* __restrict__ Sbuf) {
    int lane = threadIdx.x & 15;
    int grp = (blockIdx.x * 256 + threadIdx.x) >> 4;   // b*NC*DI + c*DI + d
    int d = grp % DI_;
    int c = (grp / DI_) % NC_;
    int b = grp / (DI_ * NC_);
    float A = -__expf(A_log[d * NS_ + lane]);
    float h = 0.f, sd = 0.f;
    int t0 = c * T_;
    for (int t = t0; t < t0 + T_; t++) {
        size_t bt = (size_t)(b * L_ + t);
        float dtv = dt[bt * DI_ + d];
        float xv  = xc[bt * DI_ + d];
        float Bt  = dbc[bt * 80 + DR_ + lane];
        h = __expf(dtv * A) * h + dtv * xv * Bt;
        sd += dtv;
    }
    size_t o = (((size_t)b * NC_ + c) * DI_ + d) * NS_ + lane;
    Pbuf[o] = __expf(A * sd);
    Sbuf[o] = h;
}

// ---------------- scan pass 2: sequential combine over chunks ---------------
__global__ __launch_bounds__(256) void scan_part2(
    const float* __restrict__ P, const float* __restrict__ S,
    float* __restrict__ hin) {
    int i = blockIdx.x * 256 + threadIdx.x;   // over B*DI*NS
    int b = i / (DI_ * NS_);
    int rem = i % (DI_ * NS_);
    float h = 0.f;
    #pragma unroll
    for (int c = 0; c < NC_; c++) {
        size_t o = ((size_t)b * NC_ + c) * (DI_ * NS_) + rem;
        hin[o] = h;
        h = P[o] * h + S[o];
    }
}

// ---------------- scan pass 3: rescan chunk with init state, gate, bf16 out -
__global__ __launch_bounds__(256) void scan_part3(
    const float* __restrict__ dt, const float* __restrict__ dbc,
    const float* __restrict__ xc, const float* __restrict__ xz,
    const float* __restrict__ A_log, const float* __restrict__ Dp,
    const float* __restrict__ hin, unsigned short* __restrict__ yg) {
    int lane = threadIdx.x & 15;
    int grp = (blockIdx.x * 256 + threadIdx.x) >> 4;
    int d = grp % DI_;
    int c = (grp / DI_) % NC_;
    int b = grp / (DI_ * NC_);
    float A = -__expf(A_log[d * NS_ + lane]);
    float Dv = Dp[d];
    float h = hin[(((size_t)b * NC_ + c) * DI_ + d) * NS_ + lane];
    int t0 = c * T_;
    for (int t = t0; t < t0 + T_; t++) {
        size_t bt = (size_t)(b * L_ + t);
        float dtv = dt[bt * DI_ + d];
        float xv  = xc[bt * DI_ + d];
        float Bt  = dbc[bt * 80 + DR_ + lane];
        float Ct  = dbc[bt * 80 + DR_ + NS_ + lane];
        h = __expf(dtv * A) * h + dtv * xv * Bt;
        float y = h * Ct;
        y += __shfl_xor(y, 1);
        y += __shfl_xor(y, 2);
        y += __shfl_xor(y, 4);
        y += __shfl_xor(y, 8);
        if (lane == 0) {
            float zv = xz[bt * (2 * DI_) + DI_ + d];
            float yy = y + xv * Dv;
            yy *= zv / (1.0f + __expf(-zv));
            yg[bt * DI_ + d] = f2bf(yy);
        }
    }
}

extern "C" void kernel_launch(void* const* d_in, const int* in_sizes, int n_in,
                              void* d_out, int out_size, void* d_ws, size_t ws_size,
                              hipStream_t stream) {
    const float* x        = (const float*)d_in[0];
    const float* ln_w     = (const float*)d_in[1];
    const float* ln_b     = (const float*)d_in[2];
    const float* in_proj  = (const float*)d_in[3];
    const float* conv_w   = (const float*)d_in[4];
    const float* conv_b   = (const float*)d_in[5];
    const float* x_proj   = (const float*)d_in[6];
    const float* dt_w     = (const float*)d_in[7];
    const float* dt_b     = (const float*)d_in[8];
    const float* A_log    = (const float*)d_in[9];
    const float* D_skip   = (const float*)d_in[10];
    const float* out_proj = (const float*)d_in[11];
    const float* fn_w     = (const float*)d_in[12];
    const float* fn_b     = (const float*)d_in[13];
    float* out = (float*)d_out;

    char* p = (char*)d_ws;
    auto alloc = [&](size_t bytes) {
        char* r = p;
        p += (bytes + 255) & ~(size_t)255;
        return (void*)r;
    };
    float* xcur = (float*)alloc((size_t)M_ * D_ * 4);
    float* res  = (float*)alloc((size_t)M_ * D_ * 4);
    unsigned short* xn = (unsigned short*)alloc((size_t)M_ * D_ * 2);
    float* xz   = (float*)alloc((size_t)M_ * 2 * DI_ * 4);
    float* xc   = (float*)alloc((size_t)M_ * DI_ * 4);
    unsigned short* xcb = (unsigned short*)alloc((size_t)M_ * DI_ * 2);
    float* dbc  = (float*)alloc((size_t)M_ * 80 * 4);
    float* dtb  = (float*)alloc((size_t)M_ * DI_ * 4);
    unsigned short* yg = (unsigned short*)alloc((size_t)M_ * DI_ * 2);
    float* Pbuf = (float*)alloc((size_t)B_ * NC_ * DI_ * NS_ * 4);
    float* Sbuf = (float*)alloc((size_t)B_ * NC_ * DI_ * NS_ * 4);
    float* hin  = (float*)alloc((size_t)B_ * NC_ * DI_ * NS_ * 4);
    float* Pb   = (float*)alloc((size_t)KS_ * M_ * 80 * 4);
    const size_t n_wi = (size_t)NL_ * 2 * DI_ * D_;   // 18.87M
    const size_t n_wo = (size_t)NL_ * D_ * DI_;       // 9.44M
    const size_t n_wx = (size_t)NL_ * 80 * DI_;       // 0.98M
    unsigned short* wi_bf = (unsigned short*)alloc(n_wi * 2);
    unsigned short* wo_bf = (unsigned short*)alloc(n_wo * 2);
    unsigned short* wx_bf = (unsigned short*)alloc(n_wx * 2);

    convert_bf16_kernel<<<(n_wi + 255) / 256, 256, 0, stream>>>(in_proj, wi_bf, (int)n_wi);
    convert_bf16_kernel<<<(n_wo + 255) / 256, 256, 0, stream>>>(out_proj, wo_bf, (int)n_wo);
    convert_bf16_kernel<<<(n_wx + 255) / 256, 256, 0, stream>>>(x_proj, wx_bf, (int)n_wx);

    init_kernel<<<(M_ * D_ + 255) / 256, 256, 0, stream>>>(x, xcur, res, M_ * D_);

    for (int l = 0; l < NL_; l++) {
        ln_res_kernel<<<M_, 256, 0, stream>>>(
            xcur, res, ln_w + l * D_, ln_b + l * D_, xn);

        // xz = xn @ Wi^T   (M=2048, N=3072, K=768)  bf16 MFMA
        gemm_bf16_kernel<<<dim3((2 * DI_) / 128, M_ / 128), 256, 0, stream>>>(
            xn, wi_bf + (size_t)l * 2 * DI_ * D_, xz, M_, 2 * DI_, D_);

        conv_silu_kernel<<<(B_ * L_ * DI_ + 255) / 256, 256, 0, stream>>>(
            xz, conv_w + l * DI_ * KC_, conv_b + l * DI_, xc, xcb);

        // dbc = xcb @ Wx^T  (M=2048, N=80, K=1536)  bf16 MFMA split-K
        xproj_gemm_kernel<<<dim3(KS_, M_ / 64), 256, 0, stream>>>(
            xcb, wx_bf + (size_t)l * 80 * DI_, Pb);
        xproj_reduce_kernel<<<(M_ * 80) / 256, 256, 0, stream>>>(Pb, dbc);

        // dt = softplus(dbc[:, :48] @ Wdt^T + bdt)  (M=2048, N=1536, K=48) fp32
        gemm_kernel<1><<<dim3(DI_ / 64, M_ / 64), 256, 0, stream>>>(
            dbc, 80, dt_w + (size_t)l * DI_ * DR_, dt_b + l * DI_,
            dtb, DI_, M_, DI_, DR_);

        // chunked selective scan
        scan_part1<<<(B_ * NC_ * DI_ * 16) / 256, 256, 0, stream>>>(
            dtb, dbc, xc, A_log + (size_t)l * DI_ * NS_, Pbuf, Sbuf);
        scan_part2<<<(B_ * DI_ * NS_) / 256, 256, 0, stream>>>(Pbuf, Sbuf, hin);
        scan_part3<<<(B_ * NC_ * DI_ * 16) / 256, 256, 0, stream>>>(
            dtb, dbc, xc, xz, A_log + (size_t)l * DI_ * NS_, D_skip + l * DI_,
            hin, yg);

        // xcur = yg @ Wo^T  (M=2048, N=768, K=1536)  bf16 MFMA
        gemm_bf16_kernel<<<dim3(D_ / 128, M_ / 128), 256, 0, stream>>>(
            yg, wo_bf + (size_t)l * D_ * DI_, xcur, M_, D_, DI_);
    }

    final_ln_kernel<<<M_, 256, 0, stream>>>(xcur, res, fn_w, fn_b, out);
}